// Round 3
// baseline (714.785 us; speedup 1.0000x reference)
//
#include <hip/hip_runtime.h>
#include <hip/hip_bf16.h>
#include <stdint.h>

#define IN_DIM 8192
#define OUT_DIM 4096
#define NNZ 1638400
#define BATCH 4096

#define BM 128
#define BN 128
#define BK 64

typedef __bf16 bf16x8 __attribute__((ext_vector_type(8)));
typedef float f32x4 __attribute__((ext_vector_type(4)));

// ---- helpers ----------------------------------------------------------------

__device__ __forceinline__ unsigned short f2bf(float f) {
  union { float f; unsigned int u; } v; v.f = f;
  unsigned int u = v.u;
  unsigned int r = (u + 0x7FFFu + ((u >> 16) & 1u)) >> 16;  // RNE
  return (unsigned short)r;
}

__device__ __forceinline__ void async16(const void* g, void* l) {
  __builtin_amdgcn_global_load_lds(
      (const __attribute__((address_space(1))) unsigned int*)g,
      (__attribute__((address_space(3))) unsigned int*)l,
      16, 0, 0);
}

// ---- scatter: 4 nnz/thread, vectorized index loads --------------------------

__device__ __forceinline__ void scatter_body(int i, const int4* __restrict__ ri4,
                                             const int4* __restrict__ ci4,
                                             const float4* __restrict__ w4,
                                             float* __restrict__ Wt) {
  int4 r = ri4[i];
  int4 c = ci4[i];
  float4 w = w4[i];
  atomicAdd(Wt + (size_t)c.x * IN_DIM + r.x, w.x);
  atomicAdd(Wt + (size_t)c.y * IN_DIM + r.y, w.y);
  atomicAdd(Wt + (size_t)c.z * IN_DIM + r.z, w.z);
  atomicAdd(Wt + (size_t)c.w * IN_DIM + r.w, w.w);
}

__device__ __forceinline__ void convert_body(int i, const float* __restrict__ src,
                                             unsigned short* __restrict__ dst) {
  const float4* s = (const float4*)src;
  float4 a = s[2 * i];
  float4 b = s[2 * i + 1];
  union { unsigned short us[8]; uint4 v; } o;
  o.us[0] = f2bf(a.x); o.us[1] = f2bf(a.y); o.us[2] = f2bf(a.z); o.us[3] = f2bf(a.w);
  o.us[4] = f2bf(b.x); o.us[5] = f2bf(b.y); o.us[6] = f2bf(b.z); o.us[7] = f2bf(b.w);
    ((uint4*)dst)[i] = o.v;
}

#define SCAT_BLOCKS (NNZ / 4 / 256)                  // 1600
#define CONV_BLOCKS ((IN_DIM * OUT_DIM) / 8 / 256)   // 16384 (same count for x)
#define ZERO_BLOCKS ((IN_DIM * OUT_DIM) / 4 / 256)   // 32768 uint4-stores of W_f32

__global__ void scatter_kernel(const int4* __restrict__ ri4,
                               const int4* __restrict__ ci4,
                               const float4* __restrict__ w4,
                               float* __restrict__ Wt) {
  scatter_body(blockIdx.x * 256 + threadIdx.x, ri4, ci4, w4, Wt);
}

__global__ void convert_kernel(const float* __restrict__ src,
                               unsigned short* __restrict__ dst) {
  convert_body(blockIdx.x * 256 + threadIdx.x, src, dst);
}

// Zero the 128 MiB fp32 W with plain uint4 stores (hipMemsetAsync graph nodes
// route to SDMA/blit at ~1 TB/s -- a store kernel hits ~5 TB/s), fused with
// the independent x fp32->bf16 conversion.
__global__ void zero_convx_kernel(uint4* __restrict__ Wt_zero,
                                  const float* __restrict__ x,
                                  unsigned short* __restrict__ x_bf16) {
  int b = blockIdx.x;
  if (b < ZERO_BLOCKS) {
    Wt_zero[b * 256 + threadIdx.x] = make_uint4(0, 0, 0, 0);
  } else {
    convert_body((b - ZERO_BLOCKS) * 256 + threadIdx.x, x, x_bf16);
  }
}

__global__ void zero_kernel(uint4* __restrict__ Wt_zero) {
  Wt_zero[blockIdx.x * 256 + threadIdx.x] = make_uint4(0, 0, 0, 0);
}

// ---- bf16 GEMM: 128x128 tile, BK=64, XOR-swizzled LDS, global_load_lds ------
// (unchanged from round 2: conflicts=0, at the m97-structure plateau ~730 TF)

__global__ __launch_bounds__(256) void gemm_kernel(
    const unsigned short* __restrict__ A,   // [BATCH][IN_DIM] bf16 bits
    const unsigned short* __restrict__ Bt,  // [OUT_DIM][IN_DIM] bf16 bits
    const float* __restrict__ bias,         // [OUT_DIM]
    float* __restrict__ C) {                // [BATCH][OUT_DIM]
  __shared__ alignas(16) unsigned short lA[BM * BK];  // 16 KiB
  __shared__ alignas(16) unsigned short lB[BN * BK];  // 16 KiB

  const int tid = threadIdx.x;
  const int m0 = blockIdx.y * BM;
  const int n0 = blockIdx.x * BN;

  const int wid = tid >> 6;
  const int lane = tid & 63;
  const int wm = wid >> 1;
  const int wn = wid & 1;
  const int quad = lane >> 4;
  const int lm = lane & 15;
  const int xorv = lm & 7;

  f32x4 acc[4][4] = {};

  int srow[4], sgs[4];
#pragma unroll
  for (int c = 0; c < 4; ++c) {
    int t2 = c * 256 + tid;
    srow[c] = t2 >> 3;
    sgs[c] = (t2 & 7) ^ (srow[c] & 7);
  }

  for (int kt = 0; kt < IN_DIM / BK; ++kt) {
    const int k0 = kt * BK;
#pragma unroll
    for (int c = 0; c < 4; ++c) {
      const int t2 = c * 256 + tid;
      async16(A + (size_t)(m0 + srow[c]) * IN_DIM + k0 + sgs[c] * 8,
              (char*)lA + t2 * 16);
      async16(Bt + (size_t)(n0 + srow[c]) * IN_DIM + k0 + sgs[c] * 8,
              (char*)lB + t2 * 16);
    }

    __syncthreads();

#pragma unroll
    for (int s = 0; s < 2; ++s) {
      bf16x8 af[4], bfr[4];
#pragma unroll
      for (int i = 0; i < 4; ++i) {
        const int row = wm * 64 + i * 16 + lm;
        const int p = ((s << 2) | quad) ^ xorv;
        af[i] = *(const bf16x8*)(lA + row * BK + p * 8);
      }
#pragma unroll
      for (int j = 0; j < 4; ++j) {
        const int row = wn * 64 + j * 16 + lm;
        const int p = ((s << 2) | quad) ^ xorv;
        bfr[j] = *(const bf16x8*)(lB + row * BK + p * 8);
      }
#pragma unroll
      for (int i = 0; i < 4; ++i)
#pragma unroll
        for (int j = 0; j < 4; ++j)
          acc[i][j] = __builtin_amdgcn_mfma_f32_16x16x32_bf16(af[i], bfr[j], acc[i][j], 0, 0, 0);
    }

    __syncthreads();
  }

  // Epilogue: C/D layout col = lane&15, row = quad*4 + reg  [m89-verified]
  const int ccol0 = n0 + wn * 64 + lm;
  const int crow0 = m0 + wm * 64;
#pragma unroll
  for (int j = 0; j < 4; ++j) {
    const int col = ccol0 + j * 16;
    const float bv = bias[col];
#pragma unroll
    for (int i = 0; i < 4; ++i) {
#pragma unroll
      for (int v = 0; v < 4; ++v) {
        const int row = crow0 + i * 16 + quad * 4 + v;
        C[(size_t)row * OUT_DIM + col] = acc[i][j][v] + bv;
      }
    }
  }
}

// ---- launch -----------------------------------------------------------------

extern "C" void kernel_launch(void* const* d_in, const int* in_sizes, int n_in,
                              void* d_out, int out_size, void* d_ws, size_t ws_size,
                              hipStream_t stream) {
  const float* x = (const float*)d_in[0];       // [4096][8192]
  const int* row_idx = (const int*)d_in[1];
  const int* col_idx = (const int*)d_in[2];
  const float* weights = (const float*)d_in[3];
  const float* bias = (const float*)d_in[4];
  float* out = (float*)d_out;                   // [4096][4096]

  const size_t W_F32_BYTES = (size_t)IN_DIM * OUT_DIM * 4;   // 128 MiB
  const size_t W_BF16_BYTES = (size_t)IN_DIM * OUT_DIM * 2;  // 64 MiB
  const size_t X_BF16_BYTES = (size_t)BATCH * IN_DIM * 2;    // 64 MiB

  float* Wt_f32 = (float*)d_ws;
  unsigned short* Wt_bf16 = (unsigned short*)((char*)d_ws + W_F32_BYTES);

  const int n8 = (IN_DIM * OUT_DIM) / 8;
  dim3 grid(OUT_DIM / BN, BATCH / BM);

  if (ws_size >= W_F32_BYTES + W_BF16_BYTES + X_BF16_BYTES) {
    // Layout B: x_bf16 disjoint at [192M,256M).
    unsigned short* x_bf16 =
        (unsigned short*)((char*)d_ws + W_F32_BYTES + W_BF16_BYTES);

    // 1. zero W_f32 (store kernel, not SDMA memset) + convert x, one launch
    zero_convx_kernel<<<ZERO_BLOCKS + CONV_BLOCKS, 256, 0, stream>>>(
        (uint4*)Wt_f32, x, x_bf16);
    // 2. scatter-add
    scatter_kernel<<<SCAT_BLOCKS, 256, 0, stream>>>(
        (const int4*)row_idx, (const int4*)col_idx, (const float4*)weights, Wt_f32);
    // 3. W fp32 -> bf16
    convert_kernel<<<n8 / 256, 256, 0, stream>>>(Wt_f32, Wt_bf16);
    // 4. GEMM + bias
    gemm_kernel<<<grid, 256, 0, stream>>>(x_bf16, Wt_bf16, bias, out);
  } else {
    // Layout A (ws >= 192 MiB): x_bf16 reuses dead Wt_f32 space.
    unsigned short* x_bf16 = (unsigned short*)d_ws;

    zero_kernel<<<ZERO_BLOCKS, 256, 0, stream>>>((uint4*)Wt_f32);
    scatter_kernel<<<SCAT_BLOCKS, 256, 0, stream>>>(
        (const int4*)row_idx, (const int4*)col_idx, (const float4*)weights, Wt_f32);
    convert_kernel<<<n8 / 256, 256, 0, stream>>>(Wt_f32, Wt_bf16);
    convert_kernel<<<n8 / 256, 256, 0, stream>>>(x, x_bf16);
    gemm_kernel<<<grid, 256, 0, stream>>>(x_bf16, Wt_bf16, bias, out);
  }
}

// Round 4
// 594.156 us; speedup vs baseline: 1.2030x; 1.2030x over previous
//
#include <hip/hip_runtime.h>
#include <hip/hip_bf16.h>
#include <stdint.h>

#define IN_DIM 8192
#define OUT_DIM 4096
#define NNZ 1638400
#define BATCH 4096

#define BM 128
#define BN 128
#define BK 64

typedef __bf16 bf16x8 __attribute__((ext_vector_type(8)));
typedef float f32x4 __attribute__((ext_vector_type(4)));

// ---- helpers ----------------------------------------------------------------

__device__ __forceinline__ unsigned short f2bf(float f) {
  union { float f; unsigned int u; } v; v.f = f;
  unsigned int u = v.u;
  unsigned int r = (u + 0x7FFFu + ((u >> 16) & 1u)) >> 16;  // RNE
  return (unsigned short)r;
}

__device__ __forceinline__ float bf2f(unsigned short b) {
  union { unsigned int u; float f; } v;
  v.u = (unsigned int)b << 16;
  return v.f;
}

__device__ __forceinline__ void async16(const void* g, void* l) {
  __builtin_amdgcn_global_load_lds(
      (const __attribute__((address_space(1))) unsigned int*)g,
      (__attribute__((address_space(3))) unsigned int*)l,
      16, 0, 0);
}

__device__ __forceinline__ void convert_body(int i, const float* __restrict__ src,
                                             unsigned short* __restrict__ dst) {
  const float4* s = (const float4*)src;
  float4 a = s[2 * i];
  float4 b = s[2 * i + 1];
  union { unsigned short us[8]; uint4 v; } o;
  o.us[0] = f2bf(a.x); o.us[1] = f2bf(a.y); o.us[2] = f2bf(a.z); o.us[3] = f2bf(a.w);
  o.us[4] = f2bf(b.x); o.us[5] = f2bf(b.y); o.us[6] = f2bf(b.z); o.us[7] = f2bf(b.w);
  ((uint4*)dst)[i] = o.v;
}

// ---- kernel 1: zero W_bf16 + convert x, perfectly uniform pairing -----------
// W_bf16 is 33.55M elems * 2B = 64 MiB -> 4.19M 16B-stores.
// x is 33.55M elems / 8 per thread   -> 4.19M threads. Same count: thread i
// does one zero-store AND one 8-elem conversion (no divergent halves).

#define PREP_BLOCKS ((IN_DIM * OUT_DIM) / 8 / 256)  // 16384

__global__ void prep_kernel(uint4* __restrict__ W_zero,
                            const float* __restrict__ x,
                            unsigned short* __restrict__ x_bf16) {
  int i = blockIdx.x * 256 + threadIdx.x;
  W_zero[i] = make_uint4(0, 0, 0, 0);
  convert_body(i, x, x_bf16);
}

// ---- kernel 2: scatter-add DIRECTLY into bf16 W via 32-bit CAS --------------
// Eliminates the 128 MiB fp32 intermediate and its 192 MB convert pass.
// Duplicates (~2.3% of nnz) accumulate with one extra bf16 rounding each
// (<=1.2e-5 per weight -- far inside the 2.36e-3 output budget).

__device__ __forceinline__ void scat1(int c, int r, float w,
                                      unsigned int* __restrict__ W) {
  size_t e = (size_t)c * IN_DIM + r;     // element index in W^T [OUT][IN]
  unsigned int* p = W + (e >> 1);
  const bool hi = (e & 1);
  unsigned int cur = *p;                 // seed (CAS corrects staleness)
  unsigned int assumed;
  do {
    assumed = cur;
    unsigned short h = hi ? (unsigned short)(assumed >> 16)
                          : (unsigned short)(assumed & 0xFFFFu);
    unsigned short nb = f2bf(bf2f(h) + w);
    unsigned int nw = hi ? ((assumed & 0x0000FFFFu) | ((unsigned int)nb << 16))
                         : ((assumed & 0xFFFF0000u) | (unsigned int)nb);
    cur = atomicCAS(p, assumed, nw);
  } while (cur != assumed);
}

#define SCAT_BLOCKS (NNZ / 4 / 256)  // 1600

__global__ void scatter_kernel(const int4* __restrict__ ri4,
                               const int4* __restrict__ ci4,
                               const float4* __restrict__ w4,
                               unsigned int* __restrict__ W) {
  int i = blockIdx.x * 256 + threadIdx.x;
  int4 r = ri4[i];
  int4 c = ci4[i];
  float4 w = w4[i];
  scat1(c.x, r.x, w.x, W);
  scat1(c.y, r.y, w.y, W);
  scat1(c.z, r.z, w.z, W);
  scat1(c.w, r.w, w.w, W);
}

// ---- kernel 3: bf16 GEMM (frozen: R2/R3 version, conflicts=0, ~730 TF) ------
// C[M,N] = A[M,K] * Bt[N,K]^T + bias. 128x128 tile, BK=64, 4 waves (2x2),
// each 64x64 via 4x4 frags of v_mfma_f32_16x16x32_bf16, global_load_lds w=16,
// XOR-swizzled 16B segments (stage-side permute, read-side inverse).

__global__ __launch_bounds__(256) void gemm_kernel(
    const unsigned short* __restrict__ A,   // [BATCH][IN_DIM] bf16 bits
    const unsigned short* __restrict__ Bt,  // [OUT_DIM][IN_DIM] bf16 bits
    const float* __restrict__ bias,         // [OUT_DIM]
    float* __restrict__ C) {                // [BATCH][OUT_DIM]
  __shared__ alignas(16) unsigned short lA[BM * BK];  // 16 KiB
  __shared__ alignas(16) unsigned short lB[BN * BK];  // 16 KiB

  const int tid = threadIdx.x;
  const int m0 = blockIdx.y * BM;
  const int n0 = blockIdx.x * BN;

  const int wid = tid >> 6;
  const int lane = tid & 63;
  const int wm = wid >> 1;
  const int wn = wid & 1;
  const int quad = lane >> 4;
  const int lm = lane & 15;
  const int xorv = lm & 7;

  f32x4 acc[4][4] = {};

  int srow[4], sgs[4];
#pragma unroll
  for (int c = 0; c < 4; ++c) {
    int t2 = c * 256 + tid;
    srow[c] = t2 >> 3;
    sgs[c] = (t2 & 7) ^ (srow[c] & 7);
  }

  for (int kt = 0; kt < IN_DIM / BK; ++kt) {
    const int k0 = kt * BK;
#pragma unroll
    for (int c = 0; c < 4; ++c) {
      const int t2 = c * 256 + tid;
      async16(A + (size_t)(m0 + srow[c]) * IN_DIM + k0 + sgs[c] * 8,
              (char*)lA + t2 * 16);
      async16(Bt + (size_t)(n0 + srow[c]) * IN_DIM + k0 + sgs[c] * 8,
              (char*)lB + t2 * 16);
    }

    __syncthreads();

#pragma unroll
    for (int s = 0; s < 2; ++s) {
      bf16x8 af[4], bfr[4];
#pragma unroll
      for (int i = 0; i < 4; ++i) {
        const int row = wm * 64 + i * 16 + lm;
        const int p = ((s << 2) | quad) ^ xorv;
        af[i] = *(const bf16x8*)(lA + row * BK + p * 8);
      }
#pragma unroll
      for (int j = 0; j < 4; ++j) {
        const int row = wn * 64 + j * 16 + lm;
        const int p = ((s << 2) | quad) ^ xorv;
        bfr[j] = *(const bf16x8*)(lB + row * BK + p * 8);
      }
#pragma unroll
      for (int i = 0; i < 4; ++i)
#pragma unroll
        for (int j = 0; j < 4; ++j)
          acc[i][j] = __builtin_amdgcn_mfma_f32_16x16x32_bf16(af[i], bfr[j], acc[i][j], 0, 0, 0);
    }

    __syncthreads();
  }

  // Epilogue: C/D layout col = lane&15, row = quad*4 + reg  [m89-verified]
  const int ccol0 = n0 + wn * 64 + lm;
  const int crow0 = m0 + wm * 64;
#pragma unroll
  for (int j = 0; j < 4; ++j) {
    const int col = ccol0 + j * 16;
    const float bv = bias[col];
#pragma unroll
    for (int i = 0; i < 4; ++i) {
#pragma unroll
      for (int v = 0; v < 4; ++v) {
        const int row = crow0 + i * 16 + quad * 4 + v;
        C[(size_t)row * OUT_DIM + col] = acc[i][j][v] + bv;
      }
    }
  }
}

// ---- launch -----------------------------------------------------------------

extern "C" void kernel_launch(void* const* d_in, const int* in_sizes, int n_in,
                              void* d_out, int out_size, void* d_ws, size_t ws_size,
                              hipStream_t stream) {
  const float* x = (const float*)d_in[0];       // [4096][8192] fp32
  const int* row_idx = (const int*)d_in[1];     // [NNZ] int32
  const int* col_idx = (const int*)d_in[2];     // [NNZ] int32
  const float* weights = (const float*)d_in[3]; // [NNZ] fp32
  const float* bias = (const float*)d_in[4];    // [4096] fp32
  float* out = (float*)d_out;                   // [4096][4096] fp32

  // ws layout: W_bf16 [0,64M), x_bf16 [64M,128M). Only 128 MiB needed now.
  const size_t W_BF16_BYTES = (size_t)IN_DIM * OUT_DIM * 2;  // 64 MiB
  unsigned short* W_bf16 = (unsigned short*)d_ws;
  unsigned short* x_bf16 = (unsigned short*)((char*)d_ws + W_BF16_BYTES);

  // 1. zero W_bf16 + convert x -> bf16 (uniform per-thread pairing)
  prep_kernel<<<PREP_BLOCKS, 256, 0, stream>>>((uint4*)W_bf16, x, x_bf16);

  // 2. scatter-add weights directly into bf16 W^T (CAS)
  scatter_kernel<<<SCAT_BLOCKS, 256, 0, stream>>>(
      (const int4*)row_idx, (const int4*)col_idx, (const float4*)weights,
      (unsigned int*)W_bf16);

  // 3. GEMM + bias
  dim3 grid(OUT_DIM / BN, BATCH / BM);
  gemm_kernel<<<grid, 256, 0, stream>>>(x_bf16, W_bf16, bias, out);
}